// Round 9
// baseline (1291.008 us; speedup 1.0000x reference)
//
#include <hip/hip_runtime.h>
#include <hip/hip_bf16.h>

using bf16 = __hip_bfloat16;
using bf16x8 = __attribute__((ext_vector_type(8))) short;   // 8 bf16 = 4 VGPRs
using f32x4  = __attribute__((ext_vector_type(4))) float;
typedef unsigned long long u64;

#define S_LEN 256
#define NBATCH 32
#define HDIM 1024
#define NBLK 256
#define SENT 0x7F7F7F7Fu   // packed bf16 pair 0x7F7F = 3.3e38: impossible for |h|<1
#define SENT64 0x7F7F7F7F7F7F7F7Full
#define GSTRIDE (8192ull * 1024ull)   // xh per-gate stride (elems)

__device__ __forceinline__ float fast_sig(float x) {
    return __builtin_amdgcn_rcpf(1.f + __expf(-x));
}
__device__ __forceinline__ float fast_tanh(float x) {
    return 1.f - 2.f * __builtin_amdgcn_rcpf(1.f + __expf(2.f * x));
}
__device__ __forceinline__ bool is_stale(u64 v) {
    return ((unsigned)v == SENT) || ((unsigned)(v >> 32) == SENT);
}

// ---------------------------------------------------------------------------
// Convert x (f32, [n][s][d]) -> xT (bf16, [s][n][d]).  Row sn = s*32+n.
// ---------------------------------------------------------------------------
__global__ __launch_bounds__(256) void convert_x(const float* __restrict__ x,
                                                 bf16* __restrict__ xT) {
    const int p = blockIdx.x;          // p = n*256 + s
    const int n = p >> 8;
    const int s = p & 255;
    const float* src = x + (size_t)p * 1024;
    bf16* dst = xT + (size_t)(s * NBATCH + n) * 1024;
#pragma unroll
    for (int j = 0; j < 4; j++) {
        const int d = threadIdx.x + j * 256;
        dst[d] = (bf16)src[d];
    }
}

// ---------------------------------------------------------------------------
// Convert + transpose: 8 matrices of 1024x1024, f32 in, bf16 out,
// out[g][c][r] = in[g][r][c]
// ---------------------------------------------------------------------------
__global__ __launch_bounds__(256) void convert_transpose_1024(const float* __restrict__ in,
                                                              bf16* __restrict__ out) {
    __shared__ float t[32][33];
    const int g  = blockIdx.z;
    const float* A = in  + (size_t)g * 1024 * 1024;
    bf16*        B = out + (size_t)g * 1024 * 1024;
    const int c0 = blockIdx.x * 32;
    const int r0 = blockIdx.y * 32;
    const int tx = threadIdx.x, ty = threadIdx.y;   // (32, 8)
#pragma unroll
    for (int j = 0; j < 32; j += 8)
        t[ty + j][tx] = A[(size_t)(r0 + ty + j) * 1024 + c0 + tx];
    __syncthreads();
#pragma unroll
    for (int j = 0; j < 32; j += 8)
        B[(size_t)(c0 + ty + j) * 1024 + r0 + tx] = (bf16)t[tx][ty + j];
}

// ---------------------------------------------------------------------------
// xh GEMM: xh[g][sn][h] = xT[sn][:] . wih[g][:][h] + bias[g][h], T out.
// 128x128 tile, BK=64, 256 thr (4 waves, 2x2), reg-staged LDS, chunk-XOR
// swizzle (16B chunk c at row r stores at c^(r&7)).
// ---------------------------------------------------------------------------
template <typename T>
__global__ __launch_bounds__(256) void xh_gemm(
        const bf16* __restrict__ xT,
        const bf16* __restrict__ wihT,
        const float* __restrict__ bias,
        T* __restrict__ xh) {
    __shared__ bf16 At[128 * 64];
    __shared__ bf16 Bt[128 * 64];
    const int g    = blockIdx.z;
    const int row0 = blockIdx.x * 128;
    const int col0 = blockIdx.y * 128;
    const int tid  = threadIdx.x;
    const int lane = tid & 63;
    const int wid  = tid >> 6;
    const int r16  = lane & 15;
    const int q    = lane >> 4;
    const int wr   = (wid >> 1) * 64;
    const int wc   = (wid & 1) * 64;
    const bf16* A = xT;
    const bf16* B = wihT + (size_t)g * 1024 * 1024;

    const f32x4 vzero = {0.f, 0.f, 0.f, 0.f};
    f32x4 acc[4][4];
#pragma unroll
    for (int m = 0; m < 4; m++)
#pragma unroll
        for (int n = 0; n < 4; n++) acc[m][n] = vzero;

    const int srow   = tid >> 3;        // 0..31
    const int skoff  = (tid & 7) * 8;   // k element offset
    const int schunk = tid & 7;         // 16B chunk index

    for (int kt = 0; kt < 16; ++kt) {
#pragma unroll
        for (int inst = 0; inst < 4; inst++) {
            const int rowA = inst * 32 + srow;
            const int sdst = rowA * 64 + ((schunk ^ (rowA & 7)) << 3);
            bf16x8 va = *(const bf16x8*)(A + (size_t)(row0 + rowA) * 1024 + kt * 64 + skoff);
            *(bf16x8*)(At + sdst) = va;
            bf16x8 vb = *(const bf16x8*)(B + (size_t)(col0 + rowA) * 1024 + kt * 64 + skoff);
            *(bf16x8*)(Bt + sdst) = vb;
        }
        __syncthreads();
#pragma unroll
        for (int it = 0; it < 2; it++) {
            bf16x8 af[4], bfr[4];
#pragma unroll
            for (int m = 0; m < 4; m++) {
                const int arow = wr + m * 16 + r16;
                af[m] = *(const bf16x8*)(At + arow * 64 + ((((it << 2) | q) ^ (arow & 7)) << 3));
            }
#pragma unroll
            for (int n = 0; n < 4; n++) {
                const int brow = wc + n * 16 + r16;
                bfr[n] = *(const bf16x8*)(Bt + brow * 64 + ((((it << 2) | q) ^ (brow & 7)) << 3));
            }
#pragma unroll
            for (int m = 0; m < 4; m++)
#pragma unroll
                for (int n = 0; n < 4; n++)
                    acc[m][n] = __builtin_amdgcn_mfma_f32_16x16x32_bf16(af[m], bfr[n], acc[m][n], 0, 0, 0);
        }
        __syncthreads();
    }
    // epilogue: C row = A-row (sn), col = B-row (h); + bias
    T* C = xh + (size_t)g * GSTRIDE;
    float bcol[4];
#pragma unroll
    for (int n = 0; n < 4; n++)
        bcol[n] = bias[g * 1024 + col0 + wc + n * 16 + r16];
#pragma unroll
    for (int m = 0; m < 4; m++)
#pragma unroll
        for (int n = 0; n < 4; n++)
#pragma unroll
            for (int j = 0; j < 4; j++)
                C[(size_t)(row0 + wr + m * 16 + q * 4 + j) * 1024 + col0 + wc + n * 16 + r16]
                    = (T)(acc[m][n][j] + bcol[n]);
}

// ---------------------------------------------------------------------------
// XCD-local persistent BiLSTM recurrence, flag-gated.
// XCD k (= blockIdx%8) owns (dir = k&1, batch group ng = k>>1); its 32 blocks
// (local = blockIdx>>3) each own 32 h-cols x 4 gates.
// ROUND-9: latency-chain + straggler-jitter pass (round 8 falsified remat:
// weights live in AGPRs; VGPR_Count counts arch-VGPRs only).
//   (a) xh/mask prefetched one step ahead, issued AFTER the h loads so the
//       compiler's counted vmcnt leaves them in flight through the MFMA
//       (in-order vmcnt: issuing them before h would couple HBM latency
//       into the h-consume wait).
//   (b) out stores moved AFTER barrier2 + flag store -> their L2/HBM ack
//       drains during the next step's flag wait, off the critical path.
//   (c) one flag CACHE LINE per block (stride 128 B: no 32-writer line) and
//       own-flag skipped in the wait (own publishes acked at barrier2).
// Sentinel backstop retained (flag gate makes it cold).
// ---------------------------------------------------------------------------
template <typename T>
__global__ __launch_bounds__(1024, 4) void lstm_rec(
        const bf16* __restrict__ whhT,
        const T* __restrict__ xh,         // [8 g][8192 sn][1024 h]
        const float* __restrict__ mask,
        unsigned* __restrict__ hstate,    // [4 slot][8 xcd][8 n][1024] bf16
        unsigned* __restrict__ flags,     // [8 xcd][32 local][32] u32 (1 line/block)
        float* __restrict__ out) {
    __shared__ float part[16 * 1024];     // [16 w][8 n][4 gate][32 col] f32 = 64 KB

    const int bi    = blockIdx.x;
    const int xcd   = bi & 7;
    const int local = bi >> 3;            // 0..31
    const int dir   = xcd & 1;
    const int ng    = xcd >> 1;           // batch group: n = ng*8 + un
    const int col0  = local * 32;
    const int tid   = threadIdx.x;
    const int w     = tid >> 6;           // wave 0..15 -> K-slice w*64
    const int lane  = tid & 63;
    const int r16   = lane & 15;
    const int q     = lane >> 4;
    const int kbase = w * 64;

    // ---- pin Whh^T: [8 colTile c][2 it] frags (held in AGPR/VGPR file).
    //      c: gate = c>>1, colsub = (c&1)*16; K: kbase + it*32 + q*8 ----
    bf16x8 bw[8][2];
#pragma unroll
    for (int c = 0; c < 8; c++) {
        const size_t rowoff =
            ((size_t)((dir * 4 + (c >> 1)) * 1024 + col0 + (c & 1) * 16 + r16)) * 1024
            + kbase + q * 8;
#pragma unroll
        for (int it = 0; it < 2; it++)
            bw[c][it] = *(const bf16x8*)(whhT + rowoff + it * 32);
    }

    // ---- update-thread state: tid<256 owns (un = tid>>5, uc = tid&31) ----
    const int un = tid >> 5;
    const int uc = tid & 31;
    float creg = 0.f, hreg = 0.f;

    const unsigned* fp = flags + (((size_t)xcd * 32 + (lane & 31)) << 5);
    const bool ownflag = (lane & 31) == local;
    const f32x4 vzero = {0.f, 0.f, 0.f, 0.f};

    // ---- prologue prefetch: xh(0) + mask(0) ----
    float xf = 0.f, xi = 0.f, xo = 0.f, xg = 0.f, mt = 0.f;
    if (tid < 256) {
        const int s0 = dir ? (S_LEN - 1) : 0;
        const size_t xb = ((size_t)(dir * 4) * GSTRIDE)
                        + ((size_t)(s0 * 32 + ng * 8 + un)) * 1024 + col0 + uc;
        xf = (float)xh[xb];
        xi = (float)xh[xb + GSTRIDE];
        xo = (float)xh[xb + 2 * GSTRIDE];
        xg = (float)xh[xb + 3 * GSTRIDE];
        mt = mask[(ng * 8 + un) * S_LEN + s0];
    }

    for (int t = 0; t < S_LEN; ++t) {
        const int s_idx = dir ? (S_LEN - 1 - t) : t;

        // ---- flag wait for step t: one line per block, own flag skipped ----
        {
            int fg = 0;
            while (true) {
                const unsigned fl = __hip_atomic_load(fp,
                    __ATOMIC_RELAXED, __HIP_MEMORY_SCOPE_AGENT);
                if (__all(ownflag || ((int)fl >= t)) || ++fg > (1 << 20)) break;
            }
        }

        // ---- bulk h read, once: lanes r16<8 read 32 B of row n=r16 ----
        u64 hq[4];
        hq[0] = 0; hq[1] = 0; hq[2] = 0; hq[3] = 0;
        const u64* Hq = (const u64*)hstate
            + ((size_t)(((t & 3) * 8 + xcd) * 8 + r16)) * 256
            + (kbase >> 2) + q * 2;
        if (r16 < 8) {
            // u64 offsets 0,1 = k [kbase+q*8, +8); offsets 8,9 = k +32 elems
            hq[0] = __hip_atomic_load(Hq,     __ATOMIC_RELAXED, __HIP_MEMORY_SCOPE_AGENT);
            hq[1] = __hip_atomic_load(Hq + 1, __ATOMIC_RELAXED, __HIP_MEMORY_SCOPE_AGENT);
            hq[2] = __hip_atomic_load(Hq + 8, __ATOMIC_RELAXED, __HIP_MEMORY_SCOPE_AGENT);
            hq[3] = __hip_atomic_load(Hq + 9, __ATOMIC_RELAXED, __HIP_MEMORY_SCOPE_AGENT);
        }

        // ---- prefetch xh(t+1) + mask(t+1): issued AFTER h loads (vmcnt) ----
        float nxf = 0.f, nxi = 0.f, nxo = 0.f, nxg = 0.f, nmt = 0.f;
        if (t + 1 < S_LEN && tid < 256) {
            const int s_nx = dir ? (S_LEN - 2 - t) : (t + 1);
            const size_t xb = ((size_t)(dir * 4) * GSTRIDE)
                            + ((size_t)(s_nx * 32 + ng * 8 + un)) * 1024 + col0 + uc;
            nxf = (float)xh[xb];
            nxi = (float)xh[xb + GSTRIDE];
            nxo = (float)xh[xb + 2 * GSTRIDE];
            nxg = (float)xh[xb + 3 * GSTRIDE];
            nmt = mask[(ng * 8 + un) * S_LEN + s_nx];
        }

        // ---- sentinel backstop (cold: flag gate makes staleness ~impossible)
        if (r16 < 8) {
            int guard = 0;
            while (true) {
                const bool st = is_stale(hq[0]) | is_stale(hq[1])
                              | is_stale(hq[2]) | is_stale(hq[3]);
                if (!st || ++guard > 8192) break;
                if (is_stale(hq[0]))
                    hq[0] = __hip_atomic_load(Hq,     __ATOMIC_RELAXED, __HIP_MEMORY_SCOPE_AGENT);
                if (is_stale(hq[1]))
                    hq[1] = __hip_atomic_load(Hq + 1, __ATOMIC_RELAXED, __HIP_MEMORY_SCOPE_AGENT);
                if (is_stale(hq[2]))
                    hq[2] = __hip_atomic_load(Hq + 8, __ATOMIC_RELAXED, __HIP_MEMORY_SCOPE_AGENT);
                if (is_stale(hq[3]))
                    hq[3] = __hip_atomic_load(Hq + 9, __ATOMIC_RELAXED, __HIP_MEMORY_SCOPE_AGENT);
            }
        }

        // ---- h(t) @ Whh^T: 16 MFMAs, partials -> LDS as we go ----
        union { u64 qv[2]; bf16x8 v; } av0, av1;
        av0.qv[0] = hq[0]; av0.qv[1] = hq[1];   // k = kbase + q*8 .. +7
        av1.qv[0] = hq[2]; av1.qv[1] = hq[3];   // k = kbase + 32 + q*8 .. +7
#pragma unroll
        for (int c = 0; c < 8; c++) {
            f32x4 a = vzero;
            a = __builtin_amdgcn_mfma_f32_16x16x32_bf16(av0.v, bw[c][0], a, 0, 0, 0);
            a = __builtin_amdgcn_mfma_f32_16x16x32_bf16(av1.v, bw[c][1], a, 0, 0, 0);
            if (lane < 32) {
#pragma unroll
                for (int j = 0; j < 4; j++)
                    part[w * 1024 + (q * 4 + j) * 128 + (c >> 1) * 32 + (c & 1) * 16 + r16]
                        = a[j];
            }
        }
        __syncthreads();

        // ---- cell update (publish only; out stores deferred past the flag) ----
        float hcar = 0.f;
        if (tid < 256) {
            // reset slot t+2 to sentinel (lockstep: nobody reads slot t+2 now)
            if ((uc & 3) == 0) {
                u64* rdst = (u64*)hstate
                    + ((size_t)((((t + 2) & 3) * 8 + xcd) * 8 + un)) * 256
                    + ((col0 + uc) >> 2);
                __hip_atomic_store(rdst, SENT64, __ATOMIC_RELAXED, __HIP_MEMORY_SCOPE_AGENT);
            }
            float pf = xf, pi = xi, po = xo, pg = xg;
#pragma unroll
            for (int ww = 0; ww < 16; ww++) {
                const float* p = part + ww * 1024 + un * 128;
                pf += p[uc];
                pi += p[32 + uc];
                po += p[64 + uc];
                pg += p[96 + uc];
            }
            const float f  = fast_sig(pf);
            const float i  = fast_sig(pi);
            const float o  = fast_sig(po);
            const float ct = fast_tanh(pg);
            creg = f * creg + i * ct;                 // c updated regardless of mask
            const float hnew = o * fast_tanh(creg);
            hcar = (mt == 0.f) ? hreg : hnew;
            hreg = hcar;
            // publish h(t+1): pack 4 cols -> u64, lanes uc&3==0 store
            union { bf16 b; unsigned short u; } cv;
            cv.b = (bf16)hcar;
            const unsigned mine  = cv.u;
            const unsigned other = (unsigned)__shfl_xor((int)mine, 1);
            const unsigned pair  = mine | (other << 16);
            const unsigned pair2 = (unsigned)__shfl_xor((int)pair, 2);
            if ((uc & 3) == 0) {
                u64* dst = (u64*)hstate
                    + ((size_t)((((t + 1) & 3) * 8 + xcd) * 8 + un)) * 256
                    + ((col0 + uc) >> 2);
                __hip_atomic_store(dst, (u64)pair | ((u64)pair2 << 32),
                                   __ATOMIC_RELAXED, __HIP_MEMORY_SCOPE_AGENT);
            }
        }
        __syncthreads();   // drains publish stores per-wave; part[] reusable

        // ---- signal ASAP: this block's h(t+1) is L2-visible ----
        if (tid == 0)
            __hip_atomic_store(flags + (((size_t)xcd * 32 + local) << 5),
                               (unsigned)(t + 1),
                               __ATOMIC_RELAXED, __HIP_MEMORY_SCOPE_AGENT);

        // ---- deferred out stores: drain during next step's flag wait ----
        if (tid < 256) {
            out[((size_t)((ng * 8 + un) * S_LEN + s_idx)) * 2048 + dir * 1024 + col0 + uc]
                = hcar * mt;
            if (t == S_LEN - 1)
                out[(size_t)NBATCH * S_LEN * 2048 + (ng * 8 + un) * 2048 + dir * 1024 + col0 + uc]
                    = hcar;
        }

        // ---- rotate prefetch ----
        xf = nxf; xi = nxi; xo = nxo; xg = nxg; mt = nmt;
    }
}

// ---------------------------------------------------------------------------
// Fallback: round-2 verified persistent kernel (51 MB workspace, 2291 µs).
// ---------------------------------------------------------------------------
__global__ __launch_bounds__(1024) void lstm_persistent(
        const bf16* __restrict__ xT,
        const bf16* __restrict__ wihT,
        const bf16* __restrict__ whhT,
        const float* __restrict__ mask,
        const float* __restrict__ bias,
        unsigned* __restrict__ hbuf,    // [4 slot][2 dir][32 n][512] u32
        float* __restrict__ out) {
    __shared__ float part[16 * 1024];

    const int bi   = blockIdx.x;
    const int dir  = bi & 1;
    const int col0 = ((bi >> 1) & 127) << 3;
    const int tid  = threadIdx.x;
    const int w    = tid >> 6;
    const int lane = tid & 63;
    const int r    = lane & 15;
    const int q    = lane >> 4;
    const int kbase = w * 64 + q * 8;

    bf16x8 bx[2][2], bh[2][2];
#pragma unroll
    for (int gp = 0; gp < 2; gp++) {
        const int gate = gp * 2 + (r >> 3);
        const size_t rowoff = ((size_t)((dir * 4 + gate) * 1024 + col0 + (r & 7))) * 1024 + kbase;
#pragma unroll
        for (int it = 0; it < 2; it++) {
            bx[gp][it] = *(const bf16x8*)(wihT + rowoff + it * 32);
            bh[gp][it] = *(const bf16x8*)(whhT + rowoff + it * 32);
        }
    }

    const int un = tid >> 3;
    const int uc = tid & 7;
    float creg = 0.f, hreg = 0.f;
    float b0 = 0.f, b1 = 0.f, b2 = 0.f, b3 = 0.f;
    if (tid < 256) {
        const int gb = (dir * 4) * 1024 + col0 + uc;
        b0 = bias[gb];
        b1 = bias[gb + 1024];
        b2 = bias[gb + 2048];
        b3 = bias[gb + 3072];
    }
    const int rx = (un & 7) * 4;

    const f32x4 vzero = {0.f, 0.f, 0.f, 0.f};
    f32x4 accA[2][2], accB[2][2];
#pragma unroll
    for (int mh = 0; mh < 2; mh++) { accB[mh][0] = vzero; accB[mh][1] = vzero; }

    {
        const int s_id = dir ? (S_LEN - 1) : 0;
        const bf16* Ax = xT + (size_t)s_id * NBATCH * HDIM + kbase;
#pragma unroll
        for (int mh = 0; mh < 2; mh++) {
            accA[mh][0] = vzero; accA[mh][1] = vzero;
#pragma unroll
            for (int it = 0; it < 2; it++) {
                bf16x8 a = *(const bf16x8*)(Ax + (size_t)(mh * 16 + r) * HDIM + it * 32);
                accA[mh][0] = __builtin_amdgcn_mfma_f32_16x16x32_bf16(a, bx[0][it], accA[mh][0], 0, 0, 0);
                accA[mh][1] = __builtin_amdgcn_mfma_f32_16x16x32_bf16(a, bx[1][it], accA[mh][1], 0, 0, 0);
            }
        }
    }

    for (int t = 0; t < S_LEN; ++t) {
        const int s_idx = dir ? (S_LEN - 1 - t) : t;
        float mt = 0.f;
        if (tid < 256) mt = mask[un * S_LEN + s_idx];

        const u64* Hp = (const u64*)hbuf
                      + ((size_t)((t & 3) * 2 + dir) * NBATCH) * 256 + (kbase >> 2);
        u64 hv[2][2][2];
#pragma unroll
        for (int mh = 0; mh < 2; mh++)
#pragma unroll
            for (int it = 0; it < 2; it++)
#pragma unroll
                for (int j = 0; j < 2; j++)
                    hv[mh][it][j] = __hip_atomic_load(
                        Hp + (size_t)(mh * 16 + r) * 256 + it * 8 + j,
                        __ATOMIC_RELAXED, __HIP_MEMORY_SCOPE_AGENT);

        if (t + 1 < S_LEN) {
            const int s_id = dir ? (S_LEN - 2 - t) : (t + 1);
            const bf16* Ax = xT + (size_t)s_id * NBATCH * HDIM + kbase;
#pragma unroll
            for (int mh = 0; mh < 2; mh++) {
                accB[mh][0] = vzero; accB[mh][1] = vzero;
#pragma unroll
                for (int it = 0; it < 2; it++) {
                    bf16x8 a = *(const bf16x8*)(Ax + (size_t)(mh * 16 + r) * HDIM + it * 32);
                    accB[mh][0] = __builtin_amdgcn_mfma_f32_16x16x32_bf16(a, bx[0][it], accB[mh][0], 0, 0, 0);
                    accB[mh][1] = __builtin_amdgcn_mfma_f32_16x16x32_bf16(a, bx[1][it], accB[mh][1], 0, 0, 0);
                }
            }
        }

        {
            int guard = 0;
            while (true) {
                bool stale = false;
#pragma unroll
                for (int mh = 0; mh < 2; mh++)
#pragma unroll
                    for (int it = 0; it < 2; it++)
#pragma unroll
                        for (int j = 0; j < 2; j++)
                            stale |= is_stale(hv[mh][it][j]);
                if (!stale || ++guard > 8192) break;
#pragma unroll
                for (int mh = 0; mh < 2; mh++)
#pragma unroll
                    for (int it = 0; it < 2; it++)
#pragma unroll
                        for (int j = 0; j < 2; j++)
                            if (is_stale(hv[mh][it][j]))
                                hv[mh][it][j] = __hip_atomic_load(
                                    Hp + (size_t)(mh * 16 + r) * 256 + it * 8 + j,
                                    __ATOMIC_RELAXED, __HIP_MEMORY_SCOPE_AGENT);
            }
        }

#pragma unroll
        for (int mh = 0; mh < 2; mh++)
#pragma unroll
            for (int it = 0; it < 2; it++) {
                union { u64 qv[2]; bf16x8 v; } av;
                av.qv[0] = hv[mh][it][0];
                av.qv[1] = hv[mh][it][1];
                accA[mh][0] = __builtin_amdgcn_mfma_f32_16x16x32_bf16(av.v, bh[0][it], accA[mh][0], 0, 0, 0);
                accA[mh][1] = __builtin_amdgcn_mfma_f32_16x16x32_bf16(av.v, bh[1][it], accA[mh][1], 0, 0, 0);
            }

        {
            float* slab = part + w * 1024;
#pragma unroll
            for (int mh = 0; mh < 2; mh++)
#pragma unroll
                for (int gp = 0; gp < 2; gp++)
#pragma unroll
                    for (int rr = 0; rr < 4; rr++) {
                        const int row = mh * 16 + q * 4 + rr;
                        const int pc = (gp * 16 + r) ^ ((row & 7) * 4);
                        slab[row * 32 + pc] = accA[mh][gp][rr];
                    }
        }
#pragma unroll
        for (int mh = 0; mh < 2; mh++) { accA[mh][0] = accB[mh][0]; accA[mh][1] = accB[mh][1]; }
        __syncthreads();

        if (tid < 256) {
            if ((uc & 3) == 0) {
                u64* rdst = (u64*)hbuf
                    + ((size_t)(((t + 2) & 3) * 2 + dir) * NBATCH + un) * 256
                    + ((col0 + uc) >> 2);
                __hip_atomic_store(rdst, SENT64, __ATOMIC_RELAXED, __HIP_MEMORY_SCOPE_AGENT);
            }
            float pf = b0, pi = b1, po = b2, pg = b3;
            const int rowbase = un * 32;
#pragma unroll
            for (int ww = 0; ww < 16; ww++) {
                const float* rowp = part + ww * 1024 + rowbase;
                pf += rowp[(0  + uc) ^ rx];
                pi += rowp[(8  + uc) ^ rx];
                po += rowp[(16 + uc) ^ rx];
                pg += rowp[(24 + uc) ^ rx];
            }
            const float f  = fast_sig(pf);
            const float i  = fast_sig(pi);
            const float o  = fast_sig(po);
            const float ct = fast_tanh(pg);
            creg = f * creg + i * ct;
            const float hnew = o * fast_tanh(creg);
            const float hcar = (mt == 0.f) ? hreg : hnew;
            hreg = hcar;
            union { bf16 b; unsigned short u; } cv;
            cv.b = (bf16)hcar;
            const unsigned mine  = cv.u;
            const unsigned other = (unsigned)__shfl_xor((int)mine, 1);
            const unsigned pair  = mine | (other << 16);
            const unsigned pair2 = (unsigned)__shfl_xor((int)pair, 2);
            if ((uc & 3) == 0) {
                u64* dst = (u64*)hbuf
                    + ((size_t)(((t + 1) & 3) * 2 + dir) * NBATCH + un) * 256
                    + ((col0 + uc) >> 2);
                __hip_atomic_store(dst, (u64)pair | ((u64)pair2 << 32),
                                   __ATOMIC_RELAXED, __HIP_MEMORY_SCOPE_AGENT);
            }
            out[((size_t)(un * S_LEN + s_idx)) * 2048 + dir * 1024 + col0 + uc] = hcar * mt;
            if (t == S_LEN - 1)
                out[(size_t)NBATCH * S_LEN * 2048 + un * 2048 + dir * 1024 + col0 + uc] = hcar;
        }
        __syncthreads();
    }
}

// ---------------------------------------------------------------------------
// Workspace layouts (adaptive on ws_size):
//   common: [0,16MB) xT | [16,32MB) wihT | [32,48MB) whhT
//   A (ws >= 319324160): xh f32 at 48MB, hstate at 318767104, flags +524288 (32KB)
//   B (ws >= 185106432): xh bf16 at 48MB, hstate at 184549376, flags +524288 (32KB)
//   C (else):            round-2 hbuf at 48MB (51 MB total, verified)
// ---------------------------------------------------------------------------
extern "C" void kernel_launch(void* const* d_in, const int* in_sizes, int n_in,
                              void* d_out, int out_size, void* d_ws, size_t ws_size,
                              hipStream_t stream) {
    const float* x    = (const float*)d_in[0];
    const float* mask = (const float*)d_in[1];
    const float* wih  = (const float*)d_in[2];
    const float* whh  = (const float*)d_in[3];
    const float* bias = (const float*)d_in[4];
    float* out = (float*)d_out;

    char* ws = (char*)d_ws;
    bf16* xT   = (bf16*)(ws);
    bf16* wihT = (bf16*)(ws + 16777216);
    bf16* whhT = (bf16*)(ws + 33554432);

    convert_x<<<NBATCH * S_LEN, 256, 0, stream>>>(x, xT);
    dim3 tb(32, 8);
    convert_transpose_1024<<<dim3(32, 32, 8), tb, 0, stream>>>(wih, wihT);
    convert_transpose_1024<<<dim3(32, 32, 8), tb, 0, stream>>>(whh, whhT);

    if (ws_size >= 319324160ull) {
        // Path A: f32 xh
        float*    xh     = (float*)(ws + 50331648);
        unsigned* hstate = (unsigned*)(ws + 318767104);
        unsigned* flags  = (unsigned*)(ws + 318767104 + 524288);
        hipMemsetAsync((char*)hstate, 0x00, 131072, stream);
        hipMemsetAsync((char*)hstate + 131072, 0x7F, 393216, stream);
        hipMemsetAsync((char*)flags, 0x00, 32768, stream);
        xh_gemm<float><<<dim3(64, 8, 8), 256, 0, stream>>>(xT, wihT, bias, xh);
        lstm_rec<float><<<256, 1024, 0, stream>>>(whhT, xh, mask, hstate, flags, out);
    } else if (ws_size >= 185106432ull) {
        // Path B: bf16 xh
        bf16*     xh     = (bf16*)(ws + 50331648);
        unsigned* hstate = (unsigned*)(ws + 184549376);
        unsigned* flags  = (unsigned*)(ws + 184549376 + 524288);
        hipMemsetAsync((char*)hstate, 0x00, 131072, stream);
        hipMemsetAsync((char*)hstate + 131072, 0x7F, 393216, stream);
        hipMemsetAsync((char*)flags, 0x00, 32768, stream);
        xh_gemm<bf16><<<dim3(64, 8, 8), 256, 0, stream>>>(xT, wihT, bias, xh);
        lstm_rec<bf16><<<256, 1024, 0, stream>>>(whhT, xh, mask, hstate, flags, out);
    } else {
        // Path C: verified round-2 fused persistent kernel
        unsigned* hbuf = (unsigned*)(ws + 50331648);
        hipMemsetAsync((char*)hbuf, 0x00, 131072, stream);
        hipMemsetAsync((char*)hbuf + 131072, 0x7F, 393216, stream);
        lstm_persistent<<<NBLK, 1024, 0, stream>>>(xT, wihT, whhT, mask, bias,
                                                   hbuf, out);
    }
}

// Round 11
// 1205.914 us; speedup vs baseline: 1.0706x; 1.0706x over previous
//
#include <hip/hip_runtime.h>
#include <hip/hip_bf16.h>

using bf16 = __hip_bfloat16;
using bf16x8 = __attribute__((ext_vector_type(8))) short;   // 8 bf16 = 4 VGPRs
using f32x4  = __attribute__((ext_vector_type(4))) float;
typedef unsigned long long u64;

#define S_LEN 256
#define NBATCH 32
#define HDIM 1024
#define NBLK 256
#define SENT 0x7F7F7F7Fu   // packed bf16 pair 0x7F7F = 3.3e38: impossible for |h|<1
#define SENT64 0x7F7F7F7F7F7F7F7Full
#define GSTRIDE (8192ull * 1024ull)   // xh per-gate stride (elems)

__device__ __forceinline__ float fast_sig(float x) {
    return __builtin_amdgcn_rcpf(1.f + __expf(-x));
}
__device__ __forceinline__ float fast_tanh(float x) {
    return 1.f - 2.f * __builtin_amdgcn_rcpf(1.f + __expf(2.f * x));
}
__device__ __forceinline__ bool is_stale(u64 v) {
    return ((unsigned)v == SENT) || ((unsigned)(v >> 32) == SENT);
}

// ---------------------------------------------------------------------------
// Convert x (f32, [n][s][d]) -> xT (bf16, [s][n][d]).  Row sn = s*32+n.
// ---------------------------------------------------------------------------
__global__ __launch_bounds__(256) void convert_x(const float* __restrict__ x,
                                                 bf16* __restrict__ xT) {
    const int p = blockIdx.x;          // p = n*256 + s
    const int n = p >> 8;
    const int s = p & 255;
    const float* src = x + (size_t)p * 1024;
    bf16* dst = xT + (size_t)(s * NBATCH + n) * 1024;
#pragma unroll
    for (int j = 0; j < 4; j++) {
        const int d = threadIdx.x + j * 256;
        dst[d] = (bf16)src[d];
    }
}

// ---------------------------------------------------------------------------
// Convert + transpose: 8 matrices of 1024x1024, f32 in, bf16 out,
// out[g][c][r] = in[g][r][c]
// ---------------------------------------------------------------------------
__global__ __launch_bounds__(256) void convert_transpose_1024(const float* __restrict__ in,
                                                              bf16* __restrict__ out) {
    __shared__ float t[32][33];
    const int g  = blockIdx.z;
    const float* A = in  + (size_t)g * 1024 * 1024;
    bf16*        B = out + (size_t)g * 1024 * 1024;
    const int c0 = blockIdx.x * 32;
    const int r0 = blockIdx.y * 32;
    const int tx = threadIdx.x, ty = threadIdx.y;   // (32, 8)
#pragma unroll
    for (int j = 0; j < 32; j += 8)
        t[ty + j][tx] = A[(size_t)(r0 + ty + j) * 1024 + c0 + tx];
    __syncthreads();
#pragma unroll
    for (int j = 0; j < 32; j += 8)
        B[(size_t)(c0 + ty + j) * 1024 + r0 + tx] = (bf16)t[tx][ty + j];
}

// ---------------------------------------------------------------------------
// xh GEMM: xh[g][sn][h] = xT[sn][:] . wih[g][:][h] + bias[g][h], T out.
// 128x128 tile, BK=64, 256 thr (4 waves, 2x2), reg-staged LDS, chunk-XOR
// swizzle (16B chunk c at row r stores at c^(r&7)).
// ---------------------------------------------------------------------------
template <typename T>
__global__ __launch_bounds__(256) void xh_gemm(
        const bf16* __restrict__ xT,
        const bf16* __restrict__ wihT,
        const float* __restrict__ bias,
        T* __restrict__ xh) {
    __shared__ bf16 At[128 * 64];
    __shared__ bf16 Bt[128 * 64];
    const int g    = blockIdx.z;
    const int row0 = blockIdx.x * 128;
    const int col0 = blockIdx.y * 128;
    const int tid  = threadIdx.x;
    const int lane = tid & 63;
    const int wid  = tid >> 6;
    const int r16  = lane & 15;
    const int q    = lane >> 4;
    const int wr   = (wid >> 1) * 64;
    const int wc   = (wid & 1) * 64;
    const bf16* A = xT;
    const bf16* B = wihT + (size_t)g * 1024 * 1024;

    const f32x4 vzero = {0.f, 0.f, 0.f, 0.f};
    f32x4 acc[4][4];
#pragma unroll
    for (int m = 0; m < 4; m++)
#pragma unroll
        for (int n = 0; n < 4; n++) acc[m][n] = vzero;

    const int srow   = tid >> 3;        // 0..31
    const int skoff  = (tid & 7) * 8;   // k element offset
    const int schunk = tid & 7;         // 16B chunk index

    for (int kt = 0; kt < 16; ++kt) {
#pragma unroll
        for (int inst = 0; inst < 4; inst++) {
            const int rowA = inst * 32 + srow;
            const int sdst = rowA * 64 + ((schunk ^ (rowA & 7)) << 3);
            bf16x8 va = *(const bf16x8*)(A + (size_t)(row0 + rowA) * 1024 + kt * 64 + skoff);
            *(bf16x8*)(At + sdst) = va;
            bf16x8 vb = *(const bf16x8*)(B + (size_t)(col0 + rowA) * 1024 + kt * 64 + skoff);
            *(bf16x8*)(Bt + sdst) = vb;
        }
        __syncthreads();
#pragma unroll
        for (int it = 0; it < 2; it++) {
            bf16x8 af[4], bfr[4];
#pragma unroll
            for (int m = 0; m < 4; m++) {
                const int arow = wr + m * 16 + r16;
                af[m] = *(const bf16x8*)(At + arow * 64 + ((((it << 2) | q) ^ (arow & 7)) << 3));
            }
#pragma unroll
            for (int n = 0; n < 4; n++) {
                const int brow = wc + n * 16 + r16;
                bfr[n] = *(const bf16x8*)(Bt + brow * 64 + ((((it << 2) | q) ^ (brow & 7)) << 3));
            }
#pragma unroll
            for (int m = 0; m < 4; m++)
#pragma unroll
                for (int n = 0; n < 4; n++)
                    acc[m][n] = __builtin_amdgcn_mfma_f32_16x16x32_bf16(af[m], bfr[n], acc[m][n], 0, 0, 0);
        }
        __syncthreads();
    }
    // epilogue: C row = A-row (sn), col = B-row (h); + bias
    T* C = xh + (size_t)g * GSTRIDE;
    float bcol[4];
#pragma unroll
    for (int n = 0; n < 4; n++)
        bcol[n] = bias[g * 1024 + col0 + wc + n * 16 + r16];
#pragma unroll
    for (int m = 0; m < 4; m++)
#pragma unroll
        for (int n = 0; n < 4; n++)
#pragma unroll
            for (int j = 0; j < 4; j++)
                C[(size_t)(row0 + wr + m * 16 + q * 4 + j) * 1024 + col0 + wc + n * 16 + r16]
                    = (T)(acc[m][n][j] + bcol[n]);
}

// ---------------------------------------------------------------------------
// XCD-local persistent BiLSTM recurrence, flag-gated.
// XCD k (= blockIdx%8) owns (dir = k&1, batch group ng = k>>1); its 32 blocks
// (local = blockIdx>>3) each own 32 h-cols x 4 gates.
// ROUND-11 = round-10 resubmitted verbatim (round 10 died to container infra,
// no kernel signal; audit found no hang/fault path — flag wait and sentinel
// sweeps are guard-bounded, protocol can't logically stall).
//   (1) SINGLE-POLLER flags: only wave 0 polls the (single) per-XCD flag
//       line, then a barrier releases the block. Round 6 had 512 waves/XCD
//       hammering one L2 line (~2.3 req/cy into a ~1/cy channel): the poll
//       queue saturated the channel and delayed both detect AND the flag
//       store's visibility. 32 pollers/XCD is below saturation.
//   (2) out stores AFTER barrier2 + flag store: barrier2 then drains only
//       publish L2-acks; out-store tail drains during the next step's wait.
//   (3) xh/mask issued AFTER the h loads (same iteration): in-order vmcnt
//       lets h be consumed without waiting on xh's HBM latency.
// Sentinel backstop retained (flag gate keeps it cold).
// ---------------------------------------------------------------------------
template <typename T>
__global__ __launch_bounds__(1024, 4) void lstm_rec(
        const bf16* __restrict__ whhT,
        const T* __restrict__ xh,         // [8 g][8192 sn][1024 h]
        const float* __restrict__ mask,
        unsigned* __restrict__ hstate,    // [4 slot][8 xcd][8 n][1024] bf16
        unsigned* __restrict__ flags,     // [8 xcd][32 local] u32, step counter
        float* __restrict__ out) {
    __shared__ float part[16 * 1024];     // [16 w][8 n][4 gate][32 col] f32 = 64 KB

    const int bi    = blockIdx.x;
    const int xcd   = bi & 7;
    const int local = bi >> 3;            // 0..31
    const int dir   = xcd & 1;
    const int ng    = xcd >> 1;           // batch group: n = ng*8 + un
    const int col0  = local * 32;
    const int tid   = threadIdx.x;
    const int w     = tid >> 6;           // wave 0..15 -> K-slice w*64
    const int lane  = tid & 63;
    const int r16   = lane & 15;
    const int q     = lane >> 4;
    const int kbase = w * 64;

    // ---- pin Whh^T: [8 colTile c][2 it] frags (AGPR/VGPR unified file).
    //      c: gate = c>>1, colsub = (c&1)*16; K: kbase + it*32 + q*8 ----
    bf16x8 bw[8][2];
#pragma unroll
    for (int c = 0; c < 8; c++) {
        const size_t rowoff =
            ((size_t)((dir * 4 + (c >> 1)) * 1024 + col0 + (c & 1) * 16 + r16)) * 1024
            + kbase + q * 8;
#pragma unroll
        for (int it = 0; it < 2; it++)
            bw[c][it] = *(const bf16x8*)(whhT + rowoff + it * 32);
    }

    // ---- update-thread state: tid<256 owns (un = tid>>5, uc = tid&31) ----
    const int un = tid >> 5;
    const int uc = tid & 31;
    float creg = 0.f, hreg = 0.f;

    const unsigned* fp = flags + xcd * 32 + (lane & 31);
    const f32x4 vzero = {0.f, 0.f, 0.f, 0.f};

    for (int t = 0; t < S_LEN; ++t) {
        const int s_idx = dir ? (S_LEN - 1 - t) : t;

        // ---- flag wait: ONLY wave 0 polls; barrier releases the block ----
        if (w == 0) {
            int fg = 0;
            while (true) {
                const unsigned fl = __hip_atomic_load(fp,
                    __ATOMIC_RELAXED, __HIP_MEMORY_SCOPE_AGENT);
                if (__all((int)fl >= t) || ++fg > (1 << 20)) break;
            }
        }
        __syncthreads();

        // ---- bulk h read, once: lanes r16<8 read 32 B of row n=r16 ----
        u64 hq[4];
        hq[0] = 0; hq[1] = 0; hq[2] = 0; hq[3] = 0;
        const u64* Hq = (const u64*)hstate
            + ((size_t)(((t & 3) * 8 + xcd) * 8 + r16)) * 256
            + (kbase >> 2) + q * 2;
        if (r16 < 8) {
            // u64 offsets 0,1 = k [kbase+q*8, +8); offsets 8,9 = k +32 elems
            hq[0] = __hip_atomic_load(Hq,     __ATOMIC_RELAXED, __HIP_MEMORY_SCOPE_AGENT);
            hq[1] = __hip_atomic_load(Hq + 1, __ATOMIC_RELAXED, __HIP_MEMORY_SCOPE_AGENT);
            hq[2] = __hip_atomic_load(Hq + 8, __ATOMIC_RELAXED, __HIP_MEMORY_SCOPE_AGENT);
            hq[3] = __hip_atomic_load(Hq + 9, __ATOMIC_RELAXED, __HIP_MEMORY_SCOPE_AGENT);
        }

        // ---- xh + mask: issued AFTER h loads; consumed in the reduce phase ----
        float xf = 0.f, xi = 0.f, xo = 0.f, xg = 0.f, mt = 0.f;
        if (tid < 256) {
            const size_t xb = ((size_t)(dir * 4) * GSTRIDE)
                            + ((size_t)(s_idx * 32 + ng * 8 + un)) * 1024 + col0 + uc;
            xf = (float)xh[xb];
            xi = (float)xh[xb + GSTRIDE];
            xo = (float)xh[xb + 2 * GSTRIDE];
            xg = (float)xh[xb + 3 * GSTRIDE];
            mt = mask[(ng * 8 + un) * S_LEN + s_idx];
        }

        // ---- sentinel backstop (cold: flag gate makes staleness ~impossible)
        if (r16 < 8) {
            int guard = 0;
            while (true) {
                const bool st = is_stale(hq[0]) | is_stale(hq[1])
                              | is_stale(hq[2]) | is_stale(hq[3]);
                if (!st || ++guard > 8192) break;
                if (is_stale(hq[0]))
                    hq[0] = __hip_atomic_load(Hq,     __ATOMIC_RELAXED, __HIP_MEMORY_SCOPE_AGENT);
                if (is_stale(hq[1]))
                    hq[1] = __hip_atomic_load(Hq + 1, __ATOMIC_RELAXED, __HIP_MEMORY_SCOPE_AGENT);
                if (is_stale(hq[2]))
                    hq[2] = __hip_atomic_load(Hq + 8, __ATOMIC_RELAXED, __HIP_MEMORY_SCOPE_AGENT);
                if (is_stale(hq[3]))
                    hq[3] = __hip_atomic_load(Hq + 9, __ATOMIC_RELAXED, __HIP_MEMORY_SCOPE_AGENT);
            }
        }

        // ---- h(t) @ Whh^T: 16 MFMAs, partials -> LDS as we go ----
        union { u64 qv[2]; bf16x8 v; } av0, av1;
        av0.qv[0] = hq[0]; av0.qv[1] = hq[1];   // k = kbase + q*8 .. +7
        av1.qv[0] = hq[2]; av1.qv[1] = hq[3];   // k = kbase + 32 + q*8 .. +7
#pragma unroll
        for (int c = 0; c < 8; c++) {
            f32x4 a = vzero;
            a = __builtin_amdgcn_mfma_f32_16x16x32_bf16(av0.v, bw[c][0], a, 0, 0, 0);
            a = __builtin_amdgcn_mfma_f32_16x16x32_bf16(av1.v, bw[c][1], a, 0, 0, 0);
            if (lane < 32) {
#pragma unroll
                for (int j = 0; j < 4; j++)
                    part[w * 1024 + (q * 4 + j) * 128 + (c >> 1) * 32 + (c & 1) * 16 + r16]
                        = a[j];
            }
        }
        __syncthreads();

        // ---- cell update (publish only; out stores deferred past the flag) ----
        float hcar = 0.f;
        if (tid < 256) {
            // reset slot t+2 to sentinel (lockstep: nobody reads slot t+2 now)
            if ((uc & 3) == 0) {
                u64* rdst = (u64*)hstate
                    + ((size_t)((((t + 2) & 3) * 8 + xcd) * 8 + un)) * 256
                    + ((col0 + uc) >> 2);
                __hip_atomic_store(rdst, SENT64, __ATOMIC_RELAXED, __HIP_MEMORY_SCOPE_AGENT);
            }
            float pf = xf, pi = xi, po = xo, pg = xg;
#pragma unroll
            for (int ww = 0; ww < 16; ww++) {
                const float* p = part + ww * 1024 + un * 128;
                pf += p[uc];
                pi += p[32 + uc];
                po += p[64 + uc];
                pg += p[96 + uc];
            }
            const float f  = fast_sig(pf);
            const float i  = fast_sig(pi);
            const float o  = fast_sig(po);
            const float ct = fast_tanh(pg);
            creg = f * creg + i * ct;                 // c updated regardless of mask
            const float hnew = o * fast_tanh(creg);
            hcar = (mt == 0.f) ? hreg : hnew;
            hreg = hcar;
            // publish h(t+1): pack 4 cols -> u64, lanes uc&3==0 store
            union { bf16 b; unsigned short u; } cv;
            cv.b = (bf16)hcar;
            const unsigned mine  = cv.u;
            const unsigned other = (unsigned)__shfl_xor((int)mine, 1);
            const unsigned pair  = mine | (other << 16);
            const unsigned pair2 = (unsigned)__shfl_xor((int)pair, 2);
            if ((uc & 3) == 0) {
                u64* dst = (u64*)hstate
                    + ((size_t)((((t + 1) & 3) * 8 + xcd) * 8 + un)) * 256
                    + ((col0 + uc) >> 2);
                __hip_atomic_store(dst, (u64)pair | ((u64)pair2 << 32),
                                   __ATOMIC_RELAXED, __HIP_MEMORY_SCOPE_AGENT);
            }
        }
        __syncthreads();   // barrier2: drains publish stores (L2 acks only)

        // ---- signal ASAP: this block's h(t+1) is L2-visible ----
        if (tid == 0)
            __hip_atomic_store(flags + xcd * 32 + local, (unsigned)(t + 1),
                               __ATOMIC_RELAXED, __HIP_MEMORY_SCOPE_AGENT);

        // ---- deferred out stores: drain during next step's flag wait ----
        if (tid < 256) {
            out[((size_t)((ng * 8 + un) * S_LEN + s_idx)) * 2048 + dir * 1024 + col0 + uc]
                = hcar * mt;
            if (t == S_LEN - 1)
                out[(size_t)NBATCH * S_LEN * 2048 + (ng * 8 + un) * 2048 + dir * 1024 + col0 + uc]
                    = hcar;
        }
    }
}

// ---------------------------------------------------------------------------
// Fallback: round-2 verified persistent kernel (51 MB workspace, 2291 µs).
// ---------------------------------------------------------------------------
__global__ __launch_bounds__(1024) void lstm_persistent(
        const bf16* __restrict__ xT,
        const bf16* __restrict__ wihT,
        const bf16* __restrict__ whhT,
        const float* __restrict__ mask,
        const float* __restrict__ bias,
        unsigned* __restrict__ hbuf,    // [4 slot][2 dir][32 n][512] u32
        float* __restrict__ out) {
    __shared__ float part[16 * 1024];

    const int bi   = blockIdx.x;
    const int dir  = bi & 1;
    const int col0 = ((bi >> 1) & 127) << 3;
    const int tid  = threadIdx.x;
    const int w    = tid >> 6;
    const int lane = tid & 63;
    const int r    = lane & 15;
    const int q    = lane >> 4;
    const int kbase = w * 64 + q * 8;

    bf16x8 bx[2][2], bh[2][2];
#pragma unroll
    for (int gp = 0; gp < 2; gp++) {
        const int gate = gp * 2 + (r >> 3);
        const size_t rowoff = ((size_t)((dir * 4 + gate) * 1024 + col0 + (r & 7))) * 1024 + kbase;
#pragma unroll
        for (int it = 0; it < 2; it++) {
            bx[gp][it] = *(const bf16x8*)(wihT + rowoff + it * 32);
            bh[gp][it] = *(const bf16x8*)(whhT + rowoff + it * 32);
        }
    }

    const int un = tid >> 3;
    const int uc = tid & 7;
    float creg = 0.f, hreg = 0.f;
    float b0 = 0.f, b1 = 0.f, b2 = 0.f, b3 = 0.f;
    if (tid < 256) {
        const int gb = (dir * 4) * 1024 + col0 + uc;
        b0 = bias[gb];
        b1 = bias[gb + 1024];
        b2 = bias[gb + 2048];
        b3 = bias[gb + 3072];
    }
    const int rx = (un & 7) * 4;

    const f32x4 vzero = {0.f, 0.f, 0.f, 0.f};
    f32x4 accA[2][2], accB[2][2];
#pragma unroll
    for (int mh = 0; mh < 2; mh++) { accB[mh][0] = vzero; accB[mh][1] = vzero; }

    {
        const int s_id = dir ? (S_LEN - 1) : 0;
        const bf16* Ax = xT + (size_t)s_id * NBATCH * HDIM + kbase;
#pragma unroll
        for (int mh = 0; mh < 2; mh++) {
            accA[mh][0] = vzero; accA[mh][1] = vzero;
#pragma unroll
            for (int it = 0; it < 2; it++) {
                bf16x8 a = *(const bf16x8*)(Ax + (size_t)(mh * 16 + r) * HDIM + it * 32);
                accA[mh][0] = __builtin_amdgcn_mfma_f32_16x16x32_bf16(a, bx[0][it], accA[mh][0], 0, 0, 0);
                accA[mh][1] = __builtin_amdgcn_mfma_f32_16x16x32_bf16(a, bx[1][it], accA[mh][1], 0, 0, 0);
            }
        }
    }

    for (int t = 0; t < S_LEN; ++t) {
        const int s_idx = dir ? (S_LEN - 1 - t) : t;
        float mt = 0.f;
        if (tid < 256) mt = mask[un * S_LEN + s_idx];

        const u64* Hp = (const u64*)hbuf
                      + ((size_t)((t & 3) * 2 + dir) * NBATCH) * 256 + (kbase >> 2);
        u64 hv[2][2][2];
#pragma unroll
        for (int mh = 0; mh < 2; mh++)
#pragma unroll
            for (int it = 0; it < 2; it++)
#pragma unroll
                for (int j = 0; j < 2; j++)
                    hv[mh][it][j] = __hip_atomic_load(
                        Hp + (size_t)(mh * 16 + r) * 256 + it * 8 + j,
                        __ATOMIC_RELAXED, __HIP_MEMORY_SCOPE_AGENT);

        if (t + 1 < S_LEN) {
            const int s_id = dir ? (S_LEN - 2 - t) : (t + 1);
            const bf16* Ax = xT + (size_t)s_id * NBATCH * HDIM + kbase;
#pragma unroll
            for (int mh = 0; mh < 2; mh++) {
                accB[mh][0] = vzero; accB[mh][1] = vzero;
#pragma unroll
                for (int it = 0; it < 2; it++) {
                    bf16x8 a = *(const bf16x8*)(Ax + (size_t)(mh * 16 + r) * HDIM + it * 32);
                    accB[mh][0] = __builtin_amdgcn_mfma_f32_16x16x32_bf16(a, bx[0][it], accB[mh][0], 0, 0, 0);
                    accB[mh][1] = __builtin_amdgcn_mfma_f32_16x16x32_bf16(a, bx[1][it], accB[mh][1], 0, 0, 0);
                }
            }
        }

        {
            int guard = 0;
            while (true) {
                bool stale = false;
#pragma unroll
                for (int mh = 0; mh < 2; mh++)
#pragma unroll
                    for (int it = 0; it < 2; it++)
#pragma unroll
                        for (int j = 0; j < 2; j++)
                            stale |= is_stale(hv[mh][it][j]);
                if (!stale || ++guard > 8192) break;
#pragma unroll
                for (int mh = 0; mh < 2; mh++)
#pragma unroll
                    for (int it = 0; it < 2; it++)
#pragma unroll
                        for (int j = 0; j < 2; j++)
                            if (is_stale(hv[mh][it][j]))
                                hv[mh][it][j] = __hip_atomic_load(
                                    Hp + (size_t)(mh * 16 + r) * 256 + it * 8 + j,
                                    __ATOMIC_RELAXED, __HIP_MEMORY_SCOPE_AGENT);
            }
        }

#pragma unroll
        for (int mh = 0; mh < 2; mh++)
#pragma unroll
            for (int it = 0; it < 2; it++) {
                union { u64 qv[2]; bf16x8 v; } av;
                av.qv[0] = hv[mh][it][0];
                av.qv[1] = hv[mh][it][1];
                accA[mh][0] = __builtin_amdgcn_mfma_f32_16x16x32_bf16(av.v, bh[0][it], accA[mh][0], 0, 0, 0);
                accA[mh][1] = __builtin_amdgcn_mfma_f32_16x16x32_bf16(av.v, bh[1][it], accA[mh][1], 0, 0, 0);
            }

        {
            float* slab = part + w * 1024;
#pragma unroll
            for (int mh = 0; mh < 2; mh++)
#pragma unroll
                for (int gp = 0; gp < 2; gp++)
#pragma unroll
                    for (int rr = 0; rr < 4; rr++) {
                        const int row = mh * 16 + q * 4 + rr;
                        const int pc = (gp * 16 + r) ^ ((row & 7) * 4);
                        slab[row * 32 + pc] = accA[mh][gp][rr];
                    }
        }
#pragma unroll
        for (int mh = 0; mh < 2; mh++) { accA[mh][0] = accB[mh][0]; accA[mh][1] = accB[mh][1]; }
        __syncthreads();

        if (tid < 256) {
            if ((uc & 3) == 0) {
                u64* rdst = (u64*)hbuf
                    + ((size_t)(((t + 2) & 3) * 2 + dir) * NBATCH + un) * 256
                    + ((col0 + uc) >> 2);
                __hip_atomic_store(rdst, SENT64, __ATOMIC_RELAXED, __HIP_MEMORY_SCOPE_AGENT);
            }
            float pf = b0, pi = b1, po = b2, pg = b3;
            const int rowbase = un * 32;
#pragma unroll
            for (int ww = 0; ww < 16; ww++) {
                const float* rowp = part + ww * 1024 + rowbase;
                pf += rowp[(0  + uc) ^ rx];
                pi += rowp[(8  + uc) ^ rx];
                po += rowp[(16 + uc) ^ rx];
                pg += rowp[(24 + uc) ^ rx];
            }
            const float f  = fast_sig(pf);
            const float i  = fast_sig(pi);
            const float o  = fast_sig(po);
            const float ct = fast_tanh(pg);
            creg = f * creg + i * ct;
            const float hnew = o * fast_tanh(creg);
            const float hcar = (mt == 0.f) ? hreg : hnew;
            hreg = hcar;
            union { bf16 b; unsigned short u; } cv;
            cv.b = (bf16)hcar;
            const unsigned mine  = cv.u;
            const unsigned other = (unsigned)__shfl_xor((int)mine, 1);
            const unsigned pair  = mine | (other << 16);
            const unsigned pair2 = (unsigned)__shfl_xor((int)pair, 2);
            if ((uc & 3) == 0) {
                u64* dst = (u64*)hbuf
                    + ((size_t)(((t + 1) & 3) * 2 + dir) * NBATCH + un) * 256
                    + ((col0 + uc) >> 2);
                __hip_atomic_store(dst, (u64)pair | ((u64)pair2 << 32),
                                   __ATOMIC_RELAXED, __HIP_MEMORY_SCOPE_AGENT);
            }
            out[((size_t)(un * S_LEN + s_idx)) * 2048 + dir * 1024 + col0 + uc] = hcar * mt;
            if (t == S_LEN - 1)
                out[(size_t)NBATCH * S_LEN * 2048 + un * 2048 + dir * 1024 + col0 + uc] = hcar;
        }
        __syncthreads();
    }
}

// ---------------------------------------------------------------------------
// Workspace layouts (adaptive on ws_size):
//   common: [0,16MB) xT | [16,32MB) wihT | [32,48MB) whhT
//   A (ws >= 319292416): xh f32 at 48MB, hstate at 318767104, flags +524288
//   B (ws >= 185074688): xh bf16 at 48MB, hstate at 184549376, flags +524288
//   C (else):            round-2 hbuf at 48MB (51 MB total, verified)
// ---------------------------------------------------------------------------
extern "C" void kernel_launch(void* const* d_in, const int* in_sizes, int n_in,
                              void* d_out, int out_size, void* d_ws, size_t ws_size,
                              hipStream_t stream) {
    const float* x    = (const float*)d_in[0];
    const float* mask = (const float*)d_in[1];
    const float* wih  = (const float*)d_in[2];
    const float* whh  = (const float*)d_in[3];
    const float* bias = (const float*)d_in[4];
    float* out = (float*)d_out;

    char* ws = (char*)d_ws;
    bf16* xT   = (bf16*)(ws);
    bf16* wihT = (bf16*)(ws + 16777216);
    bf16* whhT = (bf16*)(ws + 33554432);

    convert_x<<<NBATCH * S_LEN, 256, 0, stream>>>(x, xT);
    dim3 tb(32, 8);
    convert_transpose_1024<<<dim3(32, 32, 8), tb, 0, stream>>>(wih, wihT);
    convert_transpose_1024<<<dim3(32, 32, 8), tb, 0, stream>>>(whh, whhT);

    if (ws_size >= 319292416ull) {
        // Path A: f32 xh
        float*    xh     = (float*)(ws + 50331648);
        unsigned* hstate = (unsigned*)(ws + 318767104);
        unsigned* flags  = (unsigned*)(ws + 318767104 + 524288);
        hipMemsetAsync((char*)hstate, 0x00, 131072, stream);
        hipMemsetAsync((char*)hstate + 131072, 0x7F, 393216, stream);
        hipMemsetAsync((char*)flags, 0x00, 1024, stream);
        xh_gemm<float><<<dim3(64, 8, 8), 256, 0, stream>>>(xT, wihT, bias, xh);
        lstm_rec<float><<<256, 1024, 0, stream>>>(whhT, xh, mask, hstate, flags, out);
    } else if (ws_size >= 185074688ull) {
        // Path B: bf16 xh
        bf16*     xh     = (bf16*)(ws + 50331648);
        unsigned* hstate = (unsigned*)(ws + 184549376);
        unsigned* flags  = (unsigned*)(ws + 184549376 + 524288);
        hipMemsetAsync((char*)hstate, 0x00, 131072, stream);
        hipMemsetAsync((char*)hstate + 131072, 0x7F, 393216, stream);
        hipMemsetAsync((char*)flags, 0x00, 1024, stream);
        xh_gemm<bf16><<<dim3(64, 8, 8), 256, 0, stream>>>(xT, wihT, bias, xh);
        lstm_rec<bf16><<<256, 1024, 0, stream>>>(whhT, xh, mask, hstate, flags, out);
    } else {
        // Path C: verified round-2 fused persistent kernel
        unsigned* hbuf = (unsigned*)(ws + 50331648);
        hipMemsetAsync((char*)hbuf, 0x00, 131072, stream);
        hipMemsetAsync((char*)hbuf + 131072, 0x7F, 393216, stream);
        lstm_persistent<<<NBLK, 1024, 0, stream>>>(xT, wihT, whhT, mask, bias,
                                                   hbuf, out);
    }
}